// Round 1
// baseline (439.661 us; speedup 1.0000x reference)
//
#include <hip/hip_runtime.h>

#define PI_F 3.14159265358979323846f

// Problem constants: B=4, Cin=Cout=64, H=W=128, Wf=65, K=3
#define HH 128
#define WW 128
#define WF 65
#define NB 4
#define NC 64

// ws layout (floats): R/Z/Zi buffer [0, 4259840), Xs [4259840, 8519680), Wv [8519680, 10117120)
#define CPLX_PER_IMG (HH * WF)              // 8320
#define R_FLOATS (NB * NC * CPLX_PER_IMG * 2)   // 4,259,840

// ---------------- K1: row-wise real DFT (rfft along W) ----------------
// grid = B*C*H blocks, block = 128. R[(b*64+i)*128 + h][v] = sum_x x[..] e^{-2pi i v x /128}
__global__ __launch_bounds__(128) void k_rowfft(const float* __restrict__ x,
                                                float2* __restrict__ R) {
    __shared__ float row[HH];
    __shared__ float2 tw[HH];
    int t = threadIdx.x;
    int rid = blockIdx.x;                    // (b*64+i)*128 + h
    row[t] = x[(size_t)rid * WW + t];
    float s, c;
    __sincosf(-2.f * PI_F * (float)t / 128.f, &s, &c);
    tw[t] = make_float2(c, s);
    __syncthreads();
    if (t < WF) {
        float re = 0.f, im = 0.f;
        for (int xx = 0; xx < WW; ++xx) {
            float2 w = tw[(t * xx) & 127];
            float val = row[xx];
            re += val * w.x;
            im += val * w.y;
        }
        R[(size_t)rid * WF + t] = make_float2(re, im);
    }
}

// ---------------- K2: column complex DFT + fftshift + high-pass mask ----------------
// grid = B*C*WF blocks, block = 128. Reads column v_in of R, writes shifted/masked column of Xs.
__global__ __launch_bounds__(128) void k_colfft_shift(const float2* __restrict__ R,
                                                      float2* __restrict__ Xs) {
    __shared__ float2 col[HH];
    __shared__ float2 tw[HH];
    int t = threadIdx.x;
    int bidx = blockIdx.x;
    int v_in = bidx % WF;
    int ch = bidx / WF;                      // b*64+i
    const float2* Rc = R + (size_t)ch * CPLX_PER_IMG + v_in;
    col[t] = Rc[(size_t)t * WF];
    float s, c;
    __sincosf(-2.f * PI_F * (float)t / 128.f, &s, &c);
    tw[t] = make_float2(c, s);
    __syncthreads();
    // u_in = t
    float re = 0.f, im = 0.f;
    for (int h = 0; h < HH; ++h) {
        float2 w = tw[(t * h) & 127];
        float2 cv = col[h];
        re += cv.x * w.x - cv.y * w.y;
        im += cv.x * w.y + cv.y * w.x;
    }
    int u_out = (t + 64) & 127;              // fftshift axis -2 (roll by 64)
    int v_out = v_in + 32;                   // fftshift axis -1 (roll by 32 mod 65)
    if (v_out >= WF) v_out -= WF;
    int du = u_out - 64, dv = v_out - 64;
    bool keep = (du * du + dv * dv) > 900;   // dist > 30.0 (exact: integers)
    float2 val = keep ? make_float2(re, im) : make_float2(0.f, 0.f);
    Xs[((size_t)ch * HH + u_out) * WF + v_out] = val;
}

// ---------------- K3: Wv[o,i,p,v] = sum_q w[o,i,p,q] e^{-2pi i v q/128} ----------------
// layout: Wv[(p*65 + v)*4096 + oi]  (oi-contiguous for coalesced GEMM reads)
__global__ void k_wv(const float* __restrict__ w, float2* __restrict__ Wv) {
    int idx = blockIdx.x * blockDim.x + threadIdx.x;
    if (idx >= 3 * WF * NC * NC) return;
    int oi = idx & 4095;
    int pv = idx >> 12;
    int p = pv / WF;
    int v = pv % WF;
    const float* wp = w + (size_t)oi * 9 + p * 3;
    float re = wp[0], im = 0.f;
#pragma unroll
    for (int q = 1; q <= 2; ++q) {
        int k = (v * q) & 127;
        float s, c;
        __sincosf(-2.f * PI_F * (float)k / 128.f, &s, &c);
        re += wp[q] * c;
        im += wp[q] * s;
    }
    Wv[idx] = make_float2(re, im);
}

// ---------------- K4: per-frequency complex GEMM over Cin ----------------
// Z[b,o,u,v] = sum_i Xs[b,i,u,v] * Kf[o,i,u,v],  Kf = Wv0 + Wv1*eu1 + Wv2*eu2.
// grid = 65 * 16 blocks (v, u-chunk of 8), block = 256 (thread = b*64+o).
#define UC 8
__global__ __launch_bounds__(256) void k_gemm(const float2* __restrict__ Xs,
                                              const float2* __restrict__ Wv,
                                              float2* __restrict__ Z) {
    __shared__ float2 Kf[NC * NC];           // 32 KB [o][i]
    __shared__ float2 XsS[NB * NC];          // 2 KB  [b][i]
    int t = threadIdx.x;
    int v = blockIdx.x % WF;
    int uc = blockIdx.x / WF;
    int b = t >> 6;
    int o = t & 63;
    const float2* Wv0 = Wv + (size_t)(0 * WF + v) * 4096;
    const float2* Wv1 = Wv + (size_t)(1 * WF + v) * 4096;
    const float2* Wv2 = Wv + (size_t)(2 * WF + v) * 4096;
    for (int uu = 0; uu < UC; ++uu) {
        int u = uc * UC + uu;
        float s1, c1, s2, c2;
        __sincosf(-2.f * PI_F * (float)u / 128.f, &s1, &c1);
        __sincosf(-2.f * PI_F * (float)((2 * u) & 127) / 128.f, &s2, &c2);
        __syncthreads();                     // protect LDS from previous iteration readers
        for (int k = t; k < NC * NC; k += 256) {
            float2 w0 = Wv0[k];
            float2 w1 = Wv1[k];
            float2 w2 = Wv2[k];
            float re = w0.x + w1.x * c1 - w1.y * s1 + w2.x * c2 - w2.y * s2;
            float im = w0.y + w1.x * s1 + w1.y * c1 + w2.x * s2 + w2.y * c2;
            Kf[k] = make_float2(re, im);
        }
        {
            int bb = t >> 6, ii = t & 63;
            XsS[t] = Xs[(((size_t)(bb * NC + ii)) * HH + u) * WF + v];
        }
        __syncthreads();
        float re = 0.f, im = 0.f;
        const float2* kro = Kf + o * NC;
        const float2* xsb = XsS + b * NC;
        for (int i = 0; i < NC; ++i) {
            float2 xv = xsb[i];
            float2 kv = kro[i];
            re += xv.x * kv.x - xv.y * kv.y;
            im += xv.x * kv.y + xv.y * kv.x;
        }
        Z[(((size_t)(b * NC + o)) * HH + u) * WF + v] = make_float2(re, im);
    }
}

// ---------------- K5: inverse complex DFT along u (in place), scale 1/128 ----------------
__global__ __launch_bounds__(128) void k_ifftu(float2* __restrict__ Z) {
    __shared__ float2 col[HH];
    __shared__ float2 tw[HH];
    int t = threadIdx.x;
    int bidx = blockIdx.x;
    int v = bidx % WF;
    int ch = bidx / WF;                      // b*64+o
    float2* base = Z + (size_t)ch * CPLX_PER_IMG + v;
    col[t] = base[(size_t)t * WF];
    float s, c;
    __sincosf(2.f * PI_F * (float)t / 128.f, &s, &c);   // e^{+2pi i k/128}
    tw[t] = make_float2(c, s);
    __syncthreads();
    float re = 0.f, im = 0.f;
    for (int u = 0; u < HH; ++u) {
        float2 w = tw[(t * u) & 127];
        float2 cv = col[u];
        re += cv.x * w.x - cv.y * w.y;
        im += cv.x * w.y + cv.y * w.x;
    }
    base[(size_t)t * WF] = make_float2(re * (1.f / 128.f), im * (1.f / 128.f));
}

// ---------------- K6: c2r inverse along v (halfcomplex semantics) + bias ----------------
// out[x] = (1/128)[Re z0 + (-1)^x Re z64 + 2*sum_{v=1..63} (Re zv cos - Im zv sin)] + bias
__global__ __launch_bounds__(128) void k_irow(const float2* __restrict__ Zi,
                                              const float* __restrict__ bias,
                                              float* __restrict__ out) {
    __shared__ float2 rowc[WF];
    __shared__ float2 tw[HH];
    int t = threadIdx.x;
    int rid = blockIdx.x;                    // (b*64+o)*128 + h
    int o = (rid / HH) & 63;
    if (t < WF) rowc[t] = Zi[(size_t)rid * WF + t];
    float s, c;
    __sincosf(2.f * PI_F * (float)t / 128.f, &s, &c);
    tw[t] = make_float2(c, s);
    __syncthreads();
    float acc = rowc[0].x + ((t & 1) ? -rowc[64].x : rowc[64].x);
    for (int v = 1; v < 64; ++v) {
        float2 z = rowc[v];
        float2 w = tw[(v * t) & 127];
        acc += 2.f * (z.x * w.x - z.y * w.y);
    }
    out[(size_t)rid * WW + t] = acc * (1.f / 128.f) + bias[o];
}

extern "C" void kernel_launch(void* const* d_in, const int* in_sizes, int n_in,
                              void* d_out, int out_size, void* d_ws, size_t ws_size,
                              hipStream_t stream) {
    const float* x = (const float*)d_in[0];      // [4,64,128,128]
    const float* w = (const float*)d_in[1];      // [64,64,3,3]
    const float* bias = (const float*)d_in[2];   // [64]
    float* out = (float*)d_out;                  // [4,64,128,128]

    float* ws = (float*)d_ws;
    float2* R = (float2*)ws;                         // 17.04 MB, reused as Z then Zi
    float2* Xs = (float2*)(ws + R_FLOATS);           // 17.04 MB
    float2* Wv = (float2*)(ws + 2 * R_FLOATS);       // 6.39 MB

    k_rowfft<<<NB * NC * HH, 128, 0, stream>>>(x, R);
    k_colfft_shift<<<NB * NC * WF, 128, 0, stream>>>(R, Xs);
    k_wv<<<(3 * WF * NC * NC + 255) / 256, 256, 0, stream>>>(w, Wv);
    k_gemm<<<WF * (HH / UC), 256, 0, stream>>>(Xs, Wv, R);   // R now holds Z
    k_ifftu<<<NB * NC * WF, 128, 0, stream>>>(R);            // in-place -> Zi
    k_irow<<<NB * NC * HH, 128, 0, stream>>>(R, bias, out);
}